// Round 9
// baseline (65.004 us; speedup 1.0000x reference)
//
#include <hip/hip_runtime.h>
#include <cmath>

#define NCLS 80

// cells per level: 32*3*g*g for g in {52,26,13}
#define CELL0 259584
#define CELL1 64896
#define CELL2 16224
#define CELLT (CELL0 + CELL1 + CELL2)   // 340704

#define NBLK 240                        // mega-kernel blocks (<= 1/CU -> residency guaranteed)
#define NPER 15                         // blocks per barrier group
#define NGRP 16                         // barrier groups (NPER*NGRP == NBLK)
#define OBJ_THREADS (NBLK * 256)        // 61440
#define OBJ_TAIL (CELLT - 5 * OBJ_THREADS)  // 33504 (6th iteration bound)

// ws layout (floats):
//  [0..63]    barrier header (uint view): [0..15] grpA, [16] globA, [17] flagA,
//                                         [32..47] grpB, [48] globB
//  [TOBJ_OFF .. +CELLT)   tobj
//  [PART_OFF .. +NBLK*12) per-block targets partials {p*4 + (lbox,cls,cnt,pad)}
//  [OPART_OFF .. +NBLK*4) per-block obj partials {o0,o1,o2,pad}
#define TOBJ_OFF 64
#define PART_OFF (TOBJ_OFF + CELLT)
#define OPART_OFF (PART_OFF + NBLK * 12)

#define ZERO_F4 (CELLT / 4)             // 85176
#define NINIT_BLOCKS ((ZERO_F4 + 255) / 256)

__device__ __constant__ float c_anch[3][3][2] = {
    {{1.25f, 1.625f}, {2.0f, 3.75f}, {4.125f, 2.875f}},
    {{1.875f, 3.8125f}, {3.875f, 2.8125f}, {3.6875f, 7.4375f}},
    {{3.625f, 2.8125f}, {4.875f, 6.1875f}, {11.65625f, 10.1875f}}};
__device__ __constant__ float c_offx[5] = {0.f, 0.5f, 0.f, -0.5f, 0.f};
__device__ __constant__ float c_offy[5] = {0.f, 0.f, 0.5f, 0.f, -0.5f};

__device__ __forceinline__ float bce(float x, float y) {
    return fmaxf(x, 0.f) - x * y + log1pf(expf(-fabsf(x)));
}

// Zero tobj + barrier header.
__global__ __launch_bounds__(256) void k_init(float* __restrict__ ws) {
    const int i = blockIdx.x * 256 + threadIdx.x;
    if (blockIdx.x == 0 && threadIdx.x < 64) ws[threadIdx.x] = 0.f;
    if (i < ZERO_F4) {
        float4 z;
        z.x = 0.f; z.y = 0.f; z.z = 0.f; z.w = 0.f;
        ((float4*)(ws + TOBJ_OFF))[i] = z;
    }
}

// Hierarchical grid barrier: 16 groups x 15 (avoids flat same-address RMW serialization,
// which measures ~50-80 ns/op on this chip -> flat 240 would cost ~16 us).
__device__ __forceinline__ void grid_barrier(unsigned int* u, int bid) {
    __syncthreads();
    if (threadIdx.x == 0) {
        const int g = bid / NPER;
        const unsigned int og = __hip_atomic_fetch_add(&u[g], 1u, __ATOMIC_ACQ_REL,
                                                       __HIP_MEMORY_SCOPE_AGENT);
        if (og == (unsigned int)(NPER - 1)) {
            const unsigned int oG = __hip_atomic_fetch_add(&u[16], 1u, __ATOMIC_ACQ_REL,
                                                           __HIP_MEMORY_SCOPE_AGENT);
            if (oG == (unsigned int)(NGRP - 1))
                __hip_atomic_store(&u[17], 1u, __ATOMIC_RELEASE, __HIP_MEMORY_SCOPE_AGENT);
        }
        while (__hip_atomic_load(&u[17], __ATOMIC_ACQUIRE, __HIP_MEMORY_SCOPE_AGENT) == 0u)
            __builtin_amdgcn_s_sleep(2);
    }
    __syncthreads();
}

// Single fused kernel: targets (3 passes, pass == level) -> grid barrier ->
// obj scan -> last-block final combine.
__global__ __launch_bounds__(256) void k_mega(const float* __restrict__ p0,
                                              const float* __restrict__ p1,
                                              const float* __restrict__ p2,
                                              const float* __restrict__ tgt,
                                              float* __restrict__ ws,
                                              float* __restrict__ out) {
    unsigned int* wsu = (unsigned int*)ws;
    const int bid = blockIdx.x;
    const int lane = threadIdx.x & 63;
    const int wid = threadIdx.x >> 6;
    const int g = lane & 7;        // lane within 8-lane group
    const int grp = lane >> 3;     // group within wave
    const int m = bid * 32 + wid * 8 + grp;  // per-level entry index 0..7679
    const int o = m / 1536;        // wave-uniform (block spans 32, 1536%32==0)
    const int n = m - o * 1536;
    const int a = n >> 9;
    const int j = n & 511;

    // target row: load ONCE (same j for all 3 passes)
    const float2 t01 = *(const float2*)(tgt + j * 6 + 0);
    const float2 t23 = *(const float2*)(tgt + j * 6 + 2);
    const float2 t45 = *(const float2*)(tgt + j * 6 + 4);
    const float img = t01.x, cls = t01.y;
    const float x1 = t23.x, y1 = t23.y, x2 = t45.x, y2 = t45.y;
    const float cxn = (x1 + x2) * 0.5f, cyn = (y1 + y2) * 0.5f;  // normalized
    const float twn = x2 - x1, thn = y2 - y1;

    __shared__ float sh[4][9];

#pragma unroll
    for (int p = 0; p < 3; ++p) {
        const int gsz = (p == 0) ? 52 : ((p == 1) ? 26 : 13);
        const float* pp = (p == 0) ? p0 : ((p == 1) ? p1 : p2);
        const int toff = (p == 0) ? 0 : ((p == 1) ? CELL0 : (CELL0 + CELL1));
        const float w = (float)gsz, h = (float)gsz;
        const float gx = cxn * w, gy = cyn * h, gw = twn * w, gh = thn * h;

        const float ax = c_anch[p][a][0], ay = c_anch[p][a][1];
        const float rx = gw / ax, ry = gh / ay;
        const float mr = fmaxf(fmaxf(rx, 1.0f / rx), fmaxf(ry, 1.0f / ry));
        bool valid = (mr < 4.0f);
        if (o == 1)
            valid = valid && (gx - floorf(gx) < 0.5f) && (gx > 1.0f);
        else if (o == 2)
            valid = valid && (gy - floorf(gy) < 0.5f) && (gy > 1.0f);
        else if (o == 3) {
            const float gxi = w - gx;
            valid = valid && (gxi - floorf(gxi) < 0.5f) && (gxi > 1.0f);
        } else if (o == 4) {
            const float gyi = h - gy;
            valid = valid && (gyi - floorf(gyi) < 0.5f) && (gyi > 1.0f);
        }

        float lbox_c = 0.f, cls_c = 0.f, cnt_c = 0.f;

        if (valid) {
            const float gijx = floorf(gx - c_offx[o]);
            const float gijy = floorf(gy - c_offy[o]);
            int gi = (int)gijx;
            gi = min(max(gi, 0), gsz - 1);
            int gj = (int)gijy;
            gj = min(max(gj, 0), gsz - 1);
            const int b = (int)img;
            const int c = (int)cls;
            const int cell = ((b * 3 + a) * gsz + gj) * gsz + gi;
            const long base = (long)cell * 85;

            float x0 = 0.f, s = 0.f;
#pragma unroll
            for (int k = 0; k < 11; ++k) {
                const int elem = g + 8 * k;
                if (elem < 85) {
                    const float x = pp[base + elem];
                    if (k == 0) x0 = x;
                    if (elem >= 5) s += bce(x, (elem - 5 == c) ? 0.95f : 0.05f);
                }
            }
            cls_c = s;

            const int gb = lane & 56;
            const float t0 = __shfl(x0, gb + 0);
            const float t1 = __shfl(x0, gb + 1);
            const float t2 = __shfl(x0, gb + 2);
            const float t3 = __shfl(x0, gb + 3);

            const float sx = 1.f / (1.f + expf(-t0));
            const float sy = 1.f / (1.f + expf(-t1));
            const float sw = 1.f / (1.f + expf(-t2));
            const float shh = 1.f / (1.f + expf(-t3));
            const float pxc = sx * 2.f - 0.5f;
            const float pyc = sy * 2.f - 0.5f;
            const float pw = (sw * 2.f) * (sw * 2.f) * ax;
            const float ph = (shh * 2.f) * (shh * 2.f) * ay;

            const float tbx = gx - gijx, tby = gy - gijy, tbw = gw, tbh = gh;

            const float b1x1 = pxc - pw * 0.5f, b1x2 = pxc + pw * 0.5f;
            const float b1y1 = pyc - ph * 0.5f, b1y2 = pyc + ph * 0.5f;
            const float b2x1 = tbx - tbw * 0.5f, b2x2 = tbx + tbw * 0.5f;
            const float b2y1 = tby - tbh * 0.5f, b2y2 = tby + tbh * 0.5f;
            float iw = fminf(b1x2, b2x2) - fmaxf(b1x1, b2x1);
            iw = fmaxf(iw, 0.f);
            float ih = fminf(b1y2, b2y2) - fmaxf(b1y1, b2y1);
            ih = fmaxf(ih, 0.f);
            const float inter = iw * ih;
            const float uni = pw * ph + tbw * tbh - inter + 1e-7f;
            const float iou = inter / uni;
            const float cw = fmaxf(b1x2, b2x2) - fminf(b1x1, b2x1);
            const float ch = fmaxf(b1y2, b2y2) - fminf(b1y1, b2y1);
            const float c2 = cw * cw + ch * ch + 1e-7f;
            const float dx = b2x1 + b2x2 - b1x1 - b1x2;
            const float dy = b2y1 + b2y2 - b1y1 - b1y2;
            const float rho2 = (dx * dx + dy * dy) * 0.25f;
            const float dv = atanf(tbw / tbh) - atanf(pw / ph);
            const float v = 0.40528473f * dv * dv;  // 4/pi^2
            const float alpha = v / (v - iou + 1.0000001f);
            const float ciou = iou - (rho2 / c2 + v * alpha);

            if (g == 0) {
                lbox_c = 1.f - ciou;
                cnt_c = 1.f;
                const float score = fmaxf(ciou, 0.f);
                if (score > 0.f) {
                    unsigned int* tobj = (unsigned int*)(ws + TOBJ_OFF + toff);
                    atomicMax(tobj + cell, __float_as_uint(score));
                }
            }
        }

#pragma unroll
        for (int msk = 1; msk < 64; msk <<= 1) {
            lbox_c += __shfl_xor(lbox_c, msk);
            cls_c += __shfl_xor(cls_c, msk);
            cnt_c += __shfl_xor(cnt_c, msk);
        }
        if (lane == 0) {
            sh[wid][p * 3 + 0] = lbox_c;
            sh[wid][p * 3 + 1] = cls_c;
            sh[wid][p * 3 + 2] = cnt_c;
        }
    }
    __syncthreads();
    if (threadIdx.x == 0) {
        float* slot = ws + PART_OFF + bid * 12;
#pragma unroll
        for (int p = 0; p < 3; ++p) {
#pragma unroll
            for (int q = 0; q < 3; ++q)
                slot[p * 4 + q] = sh[0][p * 3 + q] + sh[1][p * 3 + q] +
                                  sh[2][p * 3 + q] + sh[3][p * 3 + q];
        }
    }

    // ---- grid barrier: tobj scatter + PART writes visible to all blocks ----
    grid_barrier(&wsu[0], bid);

    // ---- obj phase: 6-deep unrolled strided scan over all cells ----
    const int gtid = bid * 256 + threadIdx.x;  // 0..61439
    float v0 = 0.f, v1 = 0.f, v2 = 0.f;
#pragma unroll
    for (int u = 0; u < 6; ++u) {
        const int i = gtid + u * OBJ_THREADS;
        if (u < 5 || gtid < OBJ_TAIL) {
            float x;
            if (i < CELL0) x = p0[(long)i * 85 + 4];
            else if (i < CELL0 + CELL1) x = p1[(long)(i - CELL0) * 85 + 4];
            else x = p2[(long)(i - (CELL0 + CELL1)) * 85 + 4];
            const float t = ws[TOBJ_OFF + i];
            const float b = fmaxf(x, 0.f) - x * t + log1pf(expf(-fabsf(x)));
            if (i < CELL0) v0 += b;
            else if (i < CELL0 + CELL1) v1 += b;
            else v2 += b;
        }
    }
#pragma unroll
    for (int msk = 1; msk < 64; msk <<= 1) {
        v0 += __shfl_xor(v0, msk);
        v1 += __shfl_xor(v1, msk);
        v2 += __shfl_xor(v2, msk);
    }
    __shared__ float so[4][3];
    if (lane == 0) { so[wid][0] = v0; so[wid][1] = v1; so[wid][2] = v2; }
    __syncthreads();

    // ---- last-block election (hierarchical, no spin) ----
    __shared__ unsigned int sfin;
    if (threadIdx.x == 0) {
        sfin = 0u;
        float* slot = ws + OPART_OFF + bid * 4;
        slot[0] = so[0][0] + so[1][0] + so[2][0] + so[3][0];
        slot[1] = so[0][1] + so[1][1] + so[2][1] + so[3][1];
        slot[2] = so[0][2] + so[1][2] + so[2][2] + so[3][2];
        const int gg = bid / NPER;
        const unsigned int og = __hip_atomic_fetch_add(&wsu[32 + gg], 1u, __ATOMIC_ACQ_REL,
                                                       __HIP_MEMORY_SCOPE_AGENT);
        if (og == (unsigned int)(NPER - 1)) {
            const unsigned int oG = __hip_atomic_fetch_add(&wsu[48], 1u, __ATOMIC_ACQ_REL,
                                                           __HIP_MEMORY_SCOPE_AGENT);
            if (oG == (unsigned int)(NGRP - 1)) sfin = 1u;
        }
    }
    __syncthreads();
    if (!sfin) return;

    // ---- final combine (one block; release/acquire chain makes partials visible) ----
    float lb0 = 0.f, lb1 = 0.f, lb2 = 0.f;
    float cl0 = 0.f, cl1 = 0.f, cl2 = 0.f;
    float cn0 = 0.f, cn1 = 0.f, cn2 = 0.f;
    float ob0 = 0.f, ob1 = 0.f, ob2 = 0.f;
    if (threadIdx.x < NBLK) {
        const float* ps = ws + PART_OFF + threadIdx.x * 12;
        lb0 = ps[0]; cl0 = ps[1]; cn0 = ps[2];
        lb1 = ps[4]; cl1 = ps[5]; cn1 = ps[6];
        lb2 = ps[8]; cl2 = ps[9]; cn2 = ps[10];
        const float* os = ws + OPART_OFF + threadIdx.x * 4;
        ob0 = os[0]; ob1 = os[1]; ob2 = os[2];
    }
#pragma unroll
    for (int msk = 1; msk < 64; msk <<= 1) {
        lb0 += __shfl_xor(lb0, msk); lb1 += __shfl_xor(lb1, msk); lb2 += __shfl_xor(lb2, msk);
        cl0 += __shfl_xor(cl0, msk); cl1 += __shfl_xor(cl1, msk); cl2 += __shfl_xor(cl2, msk);
        cn0 += __shfl_xor(cn0, msk); cn1 += __shfl_xor(cn1, msk); cn2 += __shfl_xor(cn2, msk);
        ob0 += __shfl_xor(ob0, msk); ob1 += __shfl_xor(ob1, msk); ob2 += __shfl_xor(ob2, msk);
    }
    __shared__ float sf[4][12];
    if (lane == 0) {
        sf[wid][0] = lb0; sf[wid][1] = lb1; sf[wid][2] = lb2;
        sf[wid][3] = cl0; sf[wid][4] = cl1; sf[wid][5] = cl2;
        sf[wid][6] = cn0; sf[wid][7] = cn1; sf[wid][8] = cn2;
        sf[wid][9] = ob0; sf[wid][10] = ob1; sf[wid][11] = ob2;
    }
    __syncthreads();
    if (threadIdx.x == 0) {
        float lbox = 0.f, lobj = 0.f, lcls = 0.f;
        const float bal[3] = {4.0f, 1.0f, 0.4f};
        const float ncell[3] = {(float)CELL0, (float)CELL1, (float)CELL2};
        for (int l = 0; l < 3; ++l) {
            const float sbv = sf[0][l] + sf[1][l] + sf[2][l] + sf[3][l];
            const float scv = sf[0][3 + l] + sf[1][3 + l] + sf[2][3 + l] + sf[3][3 + l];
            const float snv = sf[0][6 + l] + sf[1][6 + l] + sf[2][6 + l] + sf[3][6 + l];
            const float sov = sf[0][9 + l] + sf[1][9 + l] + sf[2][9 + l] + sf[3][9 + l];
            const float nv = fmaxf(snv, 1.0f);
            lbox += sbv / nv;
            lcls += scv / (nv * (float)NCLS);
            lobj += sov / ncell[l] * bal[l];
        }
        lbox *= 0.05f;
        lcls *= 0.5f;
        const float total = (lbox + lobj + lcls) * 32.0f;
        out[0] = total;
        out[1] = lbox;
        out[2] = lobj;
        out[3] = lcls;
    }
}

extern "C" void kernel_launch(void* const* d_in, const int* in_sizes, int n_in,
                              void* d_out, int out_size, void* d_ws, size_t ws_size,
                              hipStream_t stream) {
    const float* p0 = (const float*)d_in[0];
    const float* p1 = (const float*)d_in[1];
    const float* p2 = (const float*)d_in[2];
    const float* tgt = (const float*)d_in[3];
    float* ws = (float*)d_ws;
    float* out = (float*)d_out;

    k_init<<<NINIT_BLOCKS, 256, 0, stream>>>(ws);
    k_mega<<<NBLK, 256, 0, stream>>>(p0, p1, p2, tgt, ws, out);
}